// Round 4
// baseline (129.241 us; speedup 1.0000x reference)
//
#include <hip/hip_runtime.h>
#include <hip/hip_bf16.h>
#include <hip/hip_fp16.h>
#include <math.h>

#define NB 64
#define CC 512
#define LL 256

typedef __attribute__((ext_vector_type(4))) float floatx4;
typedef __attribute__((ext_vector_type(8))) short short8;

static __device__ __forceinline__ unsigned f2bf2(float x, float y) {
    __hip_bfloat162 h = __float22bfloat162_rn(make_float2(x, y));
    union { __hip_bfloat162 h; unsigned u; } c; c.h = h;
    return c.u;   // low 16 = x, high 16 = y
}
static __device__ __forceinline__ unsigned short f2h(float x) {
    __half h = __float2half_rn(x);
    union { __half h; unsigned short u; } c; c.h = h;
    return c.u;
}
static __device__ __forceinline__ float h2f(unsigned u) {
    union { unsigned short u; __half h; } c; c.u = (unsigned short)u;
    return __half2float(c.h);
}

// decode linear t -> upper-tri (tI,tJ) of a u x u tile grid
static __device__ __forceinline__ bool decode_tile(int t, int u, int& tI, int& tJ) {
    if (t >= (u * (u + 1)) >> 1) return false;
    tI = 0;
    while (t >= u - tI) { t -= u - tI; ++tI; }
    tJ = tI + t;
    return true;
}

// ---------------- P0: gather positives -> compacted bf16 rows + norms ----------------
// bx = (slice*2+mat)*64 + n. Each block: ballot-compacts its batch, then converts
// 32 compacted rows (slice) of one matrix to bf16 and computes their norms.
// Pays the f32 read + cvt + norm ONCE instead of 5x inside the tile loop.
__global__ __launch_bounds__(256) void pack_kernel(
    const float* __restrict__ S, const float* __restrict__ T,
    const int* __restrict__ targets,
    int* __restrict__ npos, float* __restrict__ norms,
    unsigned short* __restrict__ Sc, unsigned short* __restrict__ Tc,
    float* __restrict__ out)
{
    const int bx = blockIdx.x;
    const int n = bx & (NB - 1);
    const int q = bx >> 6;
    const int mat = q & 1, slice = q >> 1;   // 16 slices x 32 rows = 512
    const int tid = threadIdx.x;
    const int w = tid >> 6, lane = tid & 63;

    __shared__ int s_idx[CC];
    __shared__ int s_cnt[8], s_off[8];
    __shared__ int s_np;

    const int* tg = targets + n * CC;
    const bool p0 = tg[tid] != 0;
    const bool p1 = tg[tid + 256] != 0;
    const unsigned long long m0 = __ballot(p0);
    const unsigned long long m1 = __ballot(p1);
    if (lane == 0) { s_cnt[w] = __popcll(m0); s_cnt[4 + w] = __popcll(m1); }
    __syncthreads();
    if (tid == 0) {
        int a = 0;
        for (int i = 0; i < 8; ++i) { s_off[i] = a; a += s_cnt[i]; }
        s_np = a;
        if (mat == 0 && slice == 0) npos[n] = a;
        if (bx == 0) out[0] = 0.0f;   // huber atomics run strictly after (stream order)
    }
    __syncthreads();
    const unsigned long long below = (1ull << lane) - 1ull;
    if (p0) s_idx[s_off[w] + __popcll(m0 & below)] = tid;
    if (p1) s_idx[s_off[4 + w] + __popcll(m1 & below)] = tid + 256;
    const int np = s_np;
    __syncthreads();

    const int r = slice * 32 + (tid >> 3);   // compacted row; 8 threads/row
    const int sub = tid & 7;                 // 32 floats per thread
    if (r >= np) return;
    const int src = s_idx[r];
    const float* P = (mat ? T : S) + ((size_t)n * CC + src) * LL + sub * 32;
    unsigned short* Q = (mat ? Tc : Sc) + ((size_t)n * CC + r) * LL + sub * 32;

    float4 v[8];
    #pragma unroll
    for (int i = 0; i < 8; ++i) v[i] = *(const float4*)(P + i * 4);
    float ns = 0.0f;
    #pragma unroll
    for (int i = 0; i < 8; ++i)
        ns += v[i].x * v[i].x + v[i].y * v[i].y + v[i].z * v[i].z + v[i].w * v[i].w;
    ns += __shfl_xor(ns, 1); ns += __shfl_xor(ns, 2); ns += __shfl_xor(ns, 4);
    if (sub == 0) norms[((size_t)mat * NB + n) * CC + r] = ns;

    uint2 o[8];
    #pragma unroll
    for (int i = 0; i < 8; ++i) o[i] = make_uint2(f2bf2(v[i].x, v[i].y), f2bf2(v[i].z, v[i].w));
    *(uint4*)(Q + 0)  = make_uint4(o[0].x, o[0].y, o[1].x, o[1].y);
    *(uint4*)(Q + 8)  = make_uint4(o[2].x, o[2].y, o[3].x, o[3].y);
    *(uint4*)(Q + 16) = make_uint4(o[4].x, o[4].y, o[5].x, o[5].y);
    *(uint4*)(Q + 24) = make_uint4(o[6].x, o[6].y, o[7].x, o[7].y);
}

// ---------------- K1: MFMA Gram + distances from compacted bf16 ----------------
// bx = (t*2+mat)*64 + n  =>  bx % 8 == n % 8 (XCD-clustered per batch; each XCD's
// working set = 8 batches x ~256 KB bf16 ~= 2 MB -> L2-resident).
// Staging is now a pure 32 B copy per lane per chunk: no cvt, no norm FMAs,
// no ballot, no idx gather. Norms come from the precomputed array.
__global__ __launch_bounds__(256) void dist_kernel(
    const unsigned short* __restrict__ Sc, const unsigned short* __restrict__ Tc,
    const int* __restrict__ npos, const float* __restrict__ norms,
    float* __restrict__ sumS, float* __restrict__ sumT,
    unsigned short* __restrict__ Ds, unsigned short* __restrict__ Dt)
{
    const int bx = blockIdx.x;
    const int n = bx & (NB - 1);
    const int q = bx >> 6;
    const int mat = q & 1, t = q >> 1;
    const int np = npos[n];
    if (np < 2) return;
    int tI, tJ;
    if (!decode_tile(t, (np + 63) >> 6, tI, tJ)) return;
    const bool diag = (tI == tJ);

    // bf16 tiles [A/B][dbuf][row][40 halves] = 20 KB
    __shared__ __align__(16) unsigned short lds[2][2][64][40];
    __shared__ float s_norm[2][64];
    __shared__ float red[4];

    const int tid = threadIdx.x;
    const int w = tid >> 6, lane = tid & 63;

    const unsigned short* Pc = (mat ? Tc : Sc) + (size_t)n * CC * LL;
    const float* nr = norms + ((size_t)mat * NB + n) * CC;
    unsigned short* Dout = (mat ? Dt : Ds) + (((size_t)t * NB + n) << 12);

    // norms -> LDS (visibility covered by the kk-loop barriers)
    if (tid < 128) {
        const int abn = tid >> 6, rn = tid & 63;
        if (!diag || abn == 0) {
            const int g = (abn ? tJ : tI) * 64 + rn;
            s_norm[abn][rn] = nr[(g < np) ? g : (np - 1)];
        }
    }

    // staging: logical rows 0..127 = A rows 0..63 then B rows 64..127 (diag: A only)
    const int srow = w * 32 + (lane >> 1);
    const int half = lane & 1;                 // which 32 B half of the row's 64 B chunk
    const bool stager = diag ? (srow < 64) : true;
    const int ab = srow >> 6, rloc = srow & 63;
    const int gk = (ab ? tJ : tI) * 64 + rloc;
    const int crow = (gk < np) ? gk : (np - 1);
    const unsigned char* rp = (const unsigned char*)(Pc + (size_t)crow * LL) + half * 32;

    uint4 pre0, pre1;
    if (stager) { pre0 = *(const uint4*)rp; pre1 = *(const uint4*)(rp + 16); }

    const int m16 = lane & 15, quad = lane >> 4;
    const int bufB = diag ? 0 : 1;
    const int wrow = w * 16;

    floatx4 acc[4];
    #pragma unroll
    for (int c = 0; c < 4; ++c) { acc[c][0] = 0; acc[c][1] = 0; acc[c][2] = 0; acc[c][3] = 0; }

    for (int kk = 0; kk < 8; ++kk) {
        const int pb = kk & 1;
        if (stager) {
            // safe: chunk kk-2's reads of buf pb drained at barrier kk-1 (lgkmcnt)
            unsigned short* dst = &lds[ab][pb][rloc][half * 16];
            *(uint4*)(dst + 0) = pre0;
            *(uint4*)(dst + 8) = pre1;
        }
        __syncthreads();   // single barrier per chunk
        if (stager && kk < 7) {                // prefetch next chunk during MFMA
            pre0 = *(const uint4*)(rp + (kk + 1) * 64);
            pre1 = *(const uint4*)(rp + (kk + 1) * 64 + 16);
        }
        const short8 a = *(const short8*)&lds[0][pb][wrow + m16][quad * 8];
        #pragma unroll
        for (int c = 0; c < 4; ++c) {
            const short8 b = *(const short8*)&lds[bufB][pb][c * 16 + m16][quad * 8];
            acc[c] = __builtin_amdgcn_mfma_f32_16x16x32_bf16(a, b, acc[c], 0, 0, 0);
        }
    }

    // ---- distances; C/D layout: col=lane&15, row=quad*4+reg ----
    float l0 = 0.0f;
    #pragma unroll
    for (int c = 0; c < 4; ++c) {
        const int colL = c * 16 + m16;
        const int gj = tJ * 64 + colL;
        const float nB = s_norm[bufB][colL];
        #pragma unroll
        for (int r = 0; r < 4; ++r) {
            const int rowL = wrow + quad * 4 + r;
            const int gi = tI * 64 + rowL;
            const float d = sqrtf(fmaxf(s_norm[0][rowL] + nB - 2.0f * acc[c][r], 1e-12f));
            if (gi < np && gj < np && gi != gj) l0 += d;
            Dout[rowL * 64 + colL] = f2h(d);
        }
    }

    #pragma unroll
    for (int o = 32; o; o >>= 1) l0 += __shfl_down(l0, o);
    if (lane == 0) red[w] = l0;
    __syncthreads();
    if (tid == 0) {
        const float wgt = diag ? 1.0f : 2.0f;  // off-diag tiles mirror-counted
        (mat ? sumT : sumS)[t * NB + n] = wgt * (red[0] + red[1] + red[2] + red[3]);
    }
}

// ---------------- K2: streaming Huber over fp16 Ds/Dt ----------------
// bx = t*64 + n: same XCD as the dist blocks that wrote this tile (L2-hot).
__global__ __launch_bounds__(256) void huber_kernel(
    const int* __restrict__ npos,
    const float* __restrict__ sumS, const float* __restrict__ sumT,
    const unsigned short* __restrict__ Ds, const unsigned short* __restrict__ Dt,
    float* __restrict__ out)
{
    const int bx = blockIdx.x;
    const int n = bx & (NB - 1), t = bx >> 6;
    const int np = npos[n];
    if (np < 2) return;
    const int u = (np + 63) >> 6;
    int tI, tJ;
    if (!decode_tile(t, u, tI, tJ)) return;
    const int ntiles = (u * (u + 1)) >> 1;

    const int tid = threadIdx.x;
    const int w = tid >> 6, lane = tid & 63;
    __shared__ float red[4];

    // batch sums from unique slots: one wave-reduce per wave (redundant, no barrier)
    float a = 0.0f, b = 0.0f;
    if (lane < ntiles) { a = sumS[lane * NB + n]; b = sumT[lane * NB + n]; }
    #pragma unroll
    for (int o = 32; o; o >>= 1) { a += __shfl_down(a, o); b += __shfl_down(b, o); }
    a = __shfl(a, 0); b = __shfl(b, 0);

    const float cnt = (float)np * (float)(np - 1);
    const float inv_ms = cnt / a;
    const float inv_mt = cnt / b;

    const size_t slot = ((size_t)t * NB + n) << 12;
    const uint4* ps = (const uint4*)(Ds + slot);   // 4096 halves = 512 uint4
    const uint4* pt = (const uint4*)(Dt + slot);

    float h = 0.0f;
    #pragma unroll
    for (int it = 0; it < 2; ++it) {
        const int g = it * 256 + tid;              // uint4 group; 8 entries each
        const uint4 va = ps[g];
        const uint4 vb = pt[g];
        const unsigned aw[4] = { va.x, va.y, va.z, va.w };
        const unsigned bw[4] = { vb.x, vb.y, vb.z, vb.w };
        const int e0 = g * 8;
        #pragma unroll
        for (int k = 0; k < 8; ++k) {
            const int e = e0 + k;
            const int gi = tI * 64 + (e >> 6);
            const int gj = tJ * 64 + (e & 63);
            if (gi < np && gj < np && gi != gj) {
                const unsigned wa = aw[k >> 1], wb = bw[k >> 1];
                const float ds = h2f((k & 1) ? (wa >> 16) : (wa & 0xffffu));
                const float dt = h2f((k & 1) ? (wb >> 16) : (wb & 0xffffu));
                const float diff = ds * inv_ms - dt * inv_mt;
                const float ad = fabsf(diff);
                h += (ad < 1.0f) ? 0.5f * diff * diff : ad - 0.5f;
            }
        }
    }

    #pragma unroll
    for (int o = 32; o; o >>= 1) h += __shfl_down(h, o);
    if (lane == 0) red[w] = h;
    __syncthreads();
    if (tid == 0) {
        const float wgt = (tI == tJ) ? 1.0f : 2.0f;
        atomicAdd(out, wgt * (red[0] + red[1] + red[2] + red[3]) / (float)np);
    }
}

extern "C" void kernel_launch(void* const* d_in, const int* in_sizes, int n_in,
                              void* d_out, int out_size, void* d_ws, size_t ws_size,
                              hipStream_t stream) {
    const float* S = (const float*)d_in[0];
    const float* T = (const float*)d_in[1];
    const int* targets = (const int*)d_in[2];
    float* out = (float*)d_out;

    char* p = (char*)d_ws;
    int* npos = (int*)p;       p += 256;                        // 64 ints (padded)
    float* norms = (float*)p;  p += (size_t)2 * NB * CC * 4;    // [mat][n][r] 256 KB
    float* sumS = (float*)p;   p += (size_t)36 * NB * 4;        // per-(t,n) slots
    float* sumT = (float*)p;   p += (size_t)36 * NB * 4;
    p = (char*)(((size_t)p + 255) & ~(size_t)255);
    unsigned short* Sc = (unsigned short*)p;  p += (size_t)NB * CC * LL * 2;   // 16.8 MB
    unsigned short* Tc = (unsigned short*)p;  p += (size_t)NB * CC * LL * 2;   // 16.8 MB
    unsigned short* Ds = (unsigned short*)p;  p += (size_t)36 * NB * 4096 * 2; // 18.9 MB
    unsigned short* Dt = (unsigned short*)p;                                   // 18.9 MB

    pack_kernel<<<32 * NB, 256, 0, stream>>>(S, T, targets, npos, norms, Sc, Tc, out);
    dist_kernel<<<72 * NB, 256, 0, stream>>>(Sc, Tc, npos, norms, sumS, sumT, Ds, Dt);
    huber_kernel<<<36 * NB, 256, 0, stream>>>(npos, sumS, sumT, Ds, Dt, out);
}